// Round 2
// baseline (1882.134 us; speedup 1.0000x reference)
//
#include <hip/hip_runtime.h>

// CrossNet B=16384, D=1024, 4 layers — single persistent kernel, take 2.
//
// Round-1 failure: 512 blk x 256 thr needed 128 VGPRs of residual per
// thread + working set > the allocator's budget -> res spilled to scratch
// -> 830 MB of HBM traffic at 578 GB/s. Fix: halve per-thread state.
//
//   grid = 256 blocks x 1024 threads  (1 block/CU, 16 waves/CU)
//   res/thread = 16 rows x 4 cols = 16 float4 = 64 VGPRs
//   __launch_bounds__(1024, 4) -> 4 waves/SIMD -> VGPR cap 128
//   => 64 res + ~50 working fits WITHOUT spill.
//
// Block owns 64 rows: 4 rowgroups (4 waves each) x 16 rows/thread.
// Row dot reduces across 256 threads: wave-64 butterfly + 4-wide LDS.
// Column partials: (256 blk x 4 rowgroups) = 1024 partial rows.
// 2 grid barriers per layer (partials ready; scale/shift ready).
// BN applied to register-resident residual; single output store at end.

#define BB 16384
#define DD 1024
#define NL 4
#define BN_EPS 1e-5f

#define GRID_   256   // = #CUs; 1 block/CU co-resident (launch_bounds caps VGPR)
#define NTHR    1024
#define RG      4     // rowgroups per block (NTHR / 256)
#define RPT     16    // rows per thread (64 rows/block / RG)
#define CHUNK   4
#define NCHUNK  4     // RPT / CHUNK
#define NP      (GRID_ * RG)   // 1024 partial rows
#define NSYNC   8     // 2 barriers per layer

// All-resident grid barrier (worked in round 1 — correctness verified).
__device__ __forceinline__ void grid_barrier(unsigned int* sync_, int slot) {
    __threadfence();
    __syncthreads();
    if (threadIdx.x == 0) {
        atomicAdd(sync_ + slot, 1u);   // device scope by default
        while (__hip_atomic_load(sync_ + slot, __ATOMIC_ACQUIRE,
                                 __HIP_MEMORY_SCOPE_AGENT) < (unsigned)GRID_) {
            __builtin_amdgcn_s_sleep(2);
        }
    }
    __syncthreads();
    __threadfence();
}

__global__ void init_sync(unsigned int* sync_) {
    if (threadIdx.x < NSYNC) sync_[threadIdx.x] = 0u;
}

__global__ __launch_bounds__(NTHR, 4) void crossnet_persistent(
    const float* __restrict__ x,     // (B,D) input == x0
    const float* __restrict__ ww,    // (NL,D)
    const float* __restrict__ wb,    // (NL,D)
    float* __restrict__ out,         // (B,D)
    float* __restrict__ Psum,        // (NP,D) per-(block,rowgroup) col sums
    float* __restrict__ Psq,         // (NP,D) per-(block,rowgroup) col sumsq
    float* __restrict__ scale,       // (D)
    float* __restrict__ shift,       // (D)
    unsigned int* __restrict__ sync_)
{
    __shared__ __align__(16) float red[2][RG][CHUNK][4];  // [buf][rg][row][wave]

    const int tid  = threadIdx.x;
    const int lane = tid & 63;
    const int wv   = tid >> 6;        // 0..15
    const int wg   = wv & 3;          // wave within rowgroup
    const int rg   = tid >> 8;        // rowgroup 0..3
    const int c    = (tid & 255) << 2;  // this thread's 4 columns
    const int blk  = blockIdx.x;
    const int r0   = blk * (RG * RPT) + rg * RPT;   // first row of this thread

    // Residual state: 16 rows x 4 cols in VGPRs for all 4 layers.
    float4 res[RPT];
    #pragma unroll
    for (int i = 0; i < RPT; ++i)
        res[i] = *(const float4*)(x + (size_t)(r0 + i) * DD + c);

    #pragma unroll 1
    for (int l = 0; l < NL; ++l) {
        const float4 w4 = *(const float4*)(ww + l * DD + c);
        const float4 b4 = *(const float4*)(wb + l * DD + c);
        const bool first = (l == 0);

        float4 asum = make_float4(0.f, 0.f, 0.f, 0.f);
        float4 asq  = make_float4(0.f, 0.f, 0.f, 0.f);

        #pragma unroll
        for (int ch = 0; ch < NCHUNK; ++ch) {
            // Issue x0 loads early (hidden under shuffles + barrier).
            float4 xv[CHUNK];
            if (!first) {
                #pragma unroll
                for (int i = 0; i < CHUNK; ++i)
                    xv[i] = *(const float4*)(
                        x + (size_t)(r0 + ch * CHUNK + i) * DD + c);
            }

            // Row-dot partials from registers.
            float p[CHUNK];
            #pragma unroll
            for (int i = 0; i < CHUNK; ++i) {
                const float4 v = res[ch * CHUNK + i];
                p[i] = v.x * w4.x + v.y * w4.y + v.z * w4.z + v.w * w4.w;
            }
            // Wave-64 butterfly.
            #pragma unroll
            for (int off = 32; off; off >>= 1) {
                #pragma unroll
                for (int i = 0; i < CHUNK; ++i)
                    p[i] += __shfl_down(p[i], off, 64);
            }
            // Cross-wave (4 waves per rowgroup) via LDS, double-buffered.
            const int slot = ch & 1;
            if (lane == 0) {
                #pragma unroll
                for (int i = 0; i < CHUNK; ++i)
                    red[slot][rg][i][wg] = p[i];
            }
            __syncthreads();

            #pragma unroll
            for (int i = 0; i < CHUNK; ++i) {
                const float4 rr = *(const float4*)red[slot][rg][i]; // broadcast
                const float s = (rr.x + rr.y) + (rr.z + rr.w);
                float4 v = res[ch * CHUNK + i];
                const float4 xi = first ? v : xv[i];  // layer 0: x0 == res
                float4 n;
                n.x = fmaf(xi.x, s, v.x) + b4.x;
                n.y = fmaf(xi.y, s, v.y) + b4.y;
                n.z = fmaf(xi.z, s, v.z) + b4.z;
                n.w = fmaf(xi.w, s, v.w) + b4.w;
                res[ch * CHUNK + i] = n;
                asum.x += n.x; asum.y += n.y; asum.z += n.z; asum.w += n.w;
                asq.x = fmaf(n.x, n.x, asq.x);
                asq.y = fmaf(n.y, n.y, asq.y);
                asq.z = fmaf(n.z, n.z, asq.z);
                asq.w = fmaf(n.w, n.w, asq.w);
            }
        }

        // Per-(block,rowgroup) column partials; thread owns its 4 cols
        // within the rowgroup.
        const size_t prow = (size_t)(blk * RG + rg) * DD + c;
        *(float4*)(Psum + prow) = asum;
        *(float4*)(Psq  + prow) = asq;

        grid_barrier(sync_, 2 * l);

        // Column stats: block blk's wave 0 reduces columns [4*blk, 4*blk+4)
        // over all NP=1024 partial rows (lane k sums rows k, k+64, ...).
        if (wv == 0) {
            const int cj = blk * 4;
            float4 s4 = make_float4(0.f, 0.f, 0.f, 0.f);
            float4 q4 = make_float4(0.f, 0.f, 0.f, 0.f);
            #pragma unroll
            for (int i = 0; i < NP / 64; ++i) {
                const size_t off = (size_t)(lane + i * 64) * DD + cj;
                const float4 ps = *(const float4*)(Psum + off);
                const float4 pq = *(const float4*)(Psq + off);
                s4.x += ps.x; s4.y += ps.y; s4.z += ps.z; s4.w += ps.w;
                q4.x += pq.x; q4.y += pq.y; q4.z += pq.z; q4.w += pq.w;
            }
            #pragma unroll
            for (int off = 32; off; off >>= 1) {
                s4.x += __shfl_down(s4.x, off, 64);
                s4.y += __shfl_down(s4.y, off, 64);
                s4.z += __shfl_down(s4.z, off, 64);
                s4.w += __shfl_down(s4.w, off, 64);
                q4.x += __shfl_down(q4.x, off, 64);
                q4.y += __shfl_down(q4.y, off, 64);
                q4.z += __shfl_down(q4.z, off, 64);
                q4.w += __shfl_down(q4.w, off, 64);
            }
            if (lane == 0) {
                const float invB = 1.0f / BB;
                float4 mu, inv, sh;
                mu.x = s4.x * invB; mu.y = s4.y * invB;
                mu.z = s4.z * invB; mu.w = s4.w * invB;
                inv.x = rsqrtf(q4.x * invB - mu.x * mu.x + BN_EPS);
                inv.y = rsqrtf(q4.y * invB - mu.y * mu.y + BN_EPS);
                inv.z = rsqrtf(q4.z * invB - mu.z * mu.z + BN_EPS);
                inv.w = rsqrtf(q4.w * invB - mu.w * mu.w + BN_EPS);
                sh.x = -mu.x * inv.x; sh.y = -mu.y * inv.y;
                sh.z = -mu.z * inv.z; sh.w = -mu.w * inv.w;
                *(float4*)(scale + cj) = inv;
                *(float4*)(shift + cj) = sh;
            }
        }

        grid_barrier(sync_, 2 * l + 1);

        // Apply BN to the register-resident residual.
        const float4 sc4 = *(const float4*)(scale + c);
        const float4 sh4 = *(const float4*)(shift + c);
        #pragma unroll
        for (int i = 0; i < RPT; ++i) {
            float4 v = res[i];
            v.x = fmaf(v.x, sc4.x, sh4.x);
            v.y = fmaf(v.y, sc4.y, sh4.y);
            v.z = fmaf(v.z, sc4.z, sh4.z);
            v.w = fmaf(v.w, sc4.w, sh4.w);
            res[i] = v;
        }
    }

    // Final residual (post-BN of layer 3) -> output.
    #pragma unroll
    for (int i = 0; i < RPT; ++i)
        *(float4*)(out + (size_t)(r0 + i) * DD + c) = res[i];
}

extern "C" void kernel_launch(void* const* d_in, const int* in_sizes, int n_in,
                              void* d_out, int out_size, void* d_ws, size_t ws_size,
                              hipStream_t stream) {
    const float* x  = (const float*)d_in[0];   // (B, D)
    const float* ww = (const float*)d_in[1];   // (NL, D)
    const float* wb = (const float*)d_in[2];   // (NL, D)
    float* out = (float*)d_out;
    float* ws  = (float*)d_ws;

    // Workspace: 2 * NP * D + 2 * D + NSYNC floats  (~8 MB).
    float* Psum  = ws;                          // NP * D
    float* Psq   = Psum + (size_t)NP * DD;      // NP * D
    float* scale = Psq  + (size_t)NP * DD;      // D
    float* shift = scale + DD;                  // D
    unsigned int* sync_ = (unsigned int*)(shift + DD);  // NSYNC counters

    // Workspace is poisoned each iteration: re-zero barrier counters inside
    // the captured graph, before the persistent kernel.
    init_sync<<<1, 64, 0, stream>>>(sync_);
    crossnet_persistent<<<GRID_, NTHR, 0, stream>>>(
        x, ww, wb, out, Psum, Psq, scale, shift, sync_);
}

// Round 3
// 1418.932 us; speedup vs baseline: 1.3264x; 1.3264x over previous
//
#include <hip/hip_runtime.h>

// CrossNet B=16384, D=1024, 4 layers — single persistent kernel, take 3.
//
// Rounds 1-2 failure mode (from counters): VGPR_Count came out at exactly
// HALF the launch_bounds-derived cap both times (128 of 256, then 64 of
// 128), with ~0.5-1 GB of scratch traffic. __launch_bounds__'s 2nd arg is
// only a MINIMUM waves/EU; the AMDGPU allocator's occupancy heuristic
// targeted 2x that minimum and spilled the residual array to scratch to
// get there.  Fix: pin occupancy EXACTLY with amdgpu_waves_per_eu(2,2)
// -> hard VGPR budget 256/thread, no occupancy chasing.
//
//   grid = 512 blocks x 256 threads = 2 blocks/CU (co-resident: the
//   attribute FORCES VGPR <= 256, which admits >= 2 blocks/CU; LDS 128 B).
//   res/thread = 32 rows x 4 cols = 32 float4 = 128 VGPRs, + ~70 working
//   ~= 200 < 256 budget.
//
// Per layer: row dots (wave butterfly + 4-wide LDS, double-buffered
// slots, 1 syncthreads/4-row chunk), rank-1 update in registers,
// per-block column sum/sumsq partials -> grid barrier -> 256 stat blocks
// reduce 512 partials/column -> scale/shift -> grid barrier -> BN applied
// to register-resident residual. x0 loads software-pipelined one chunk
// ahead (xn -> xv rotate, all indices compile-time).
//
// Memory traffic if registers hold: x once from HBM (64 MB), x0 layers
// 1-3 from L3, 4x4 MB partials r/w, 64 MB output write. No res traffic.

#define BB 16384
#define DD 1024
#define NL 4
#define BN_EPS 1e-5f

#define GRID_   512   // 2 blocks/CU * 256 CUs (co-residency guaranteed)
#define NTHR    256
#define ROWS    32    // BB / GRID_
#define CHUNK   4
#define NCHUNK  8     // ROWS / CHUNK
#define STATB   256   // stat blocks (4 cols each, wave 0 only)
#define NSYNC   8     // 2 barriers per layer

// All-resident grid barrier (correctness verified in rounds 1-2).
__device__ __forceinline__ void grid_barrier(unsigned int* sync_, int slot) {
    __threadfence();
    __syncthreads();
    if (threadIdx.x == 0) {
        atomicAdd(sync_ + slot, 1u);   // device scope by default
        while (__hip_atomic_load(sync_ + slot, __ATOMIC_ACQUIRE,
                                 __HIP_MEMORY_SCOPE_AGENT) < (unsigned)GRID_) {
            __builtin_amdgcn_s_sleep(2);
        }
    }
    __syncthreads();
    __threadfence();
}

__global__ void init_sync(unsigned int* sync_) {
    if (threadIdx.x < NSYNC) sync_[threadIdx.x] = 0u;
}

__global__ __attribute__((amdgpu_waves_per_eu(2, 2))) __launch_bounds__(NTHR)
void crossnet_persistent(
    const float* __restrict__ x,     // (B,D) input == x0
    const float* __restrict__ ww,    // (NL,D)
    const float* __restrict__ wb,    // (NL,D)
    float* __restrict__ out,         // (B,D)
    float* __restrict__ Psum,        // (GRID_,D) per-block column sums
    float* __restrict__ Psq,         // (GRID_,D) per-block column sumsq
    float* __restrict__ scale,       // (D)
    float* __restrict__ shift,       // (D)
    unsigned int* __restrict__ sync_)
{
    __shared__ __align__(16) float red[2][CHUNK][4];  // [buf][row][wave]

    const int tid  = threadIdx.x;
    const int lane = tid & 63;
    const int wv   = tid >> 6;
    const int c    = tid << 2;           // this thread's 4 columns
    const int blk  = blockIdx.x;
    const int r0   = blk * ROWS;

    // Residual state: 32 rows x 4 cols, in VGPRs for all 4 layers.
    float4 res[ROWS];
    #pragma unroll
    for (int i = 0; i < ROWS; ++i)
        res[i] = *(const float4*)(x + (size_t)(r0 + i) * DD + c);

    #pragma unroll 1
    for (int l = 0; l < NL; ++l) {
        const float4 w4 = *(const float4*)(ww + l * DD + c);
        const float4 b4 = *(const float4*)(wb + l * DD + c);
        const bool first = (l == 0);

        float4 asum = make_float4(0.f, 0.f, 0.f, 0.f);
        float4 asq  = make_float4(0.f, 0.f, 0.f, 0.f);

        // x0 prefetch pipeline: xv = current chunk, xn = next chunk.
        float4 xv[CHUNK], xn[CHUNK];
        if (!first) {
            #pragma unroll
            for (int i = 0; i < CHUNK; ++i)
                xv[i] = *(const float4*)(x + (size_t)(r0 + i) * DD + c);
        }

        #pragma unroll
        for (int ch = 0; ch < NCHUNK; ++ch) {
            // Issue next chunk's x0 loads now; consumed after the barrier.
            if (!first && ch + 1 < NCHUNK) {
                #pragma unroll
                for (int i = 0; i < CHUNK; ++i)
                    xn[i] = *(const float4*)(
                        x + (size_t)(r0 + (ch + 1) * CHUNK + i) * DD + c);
            }

            // Row-dot partials from registers.
            float p[CHUNK];
            #pragma unroll
            for (int i = 0; i < CHUNK; ++i) {
                const float4 v = res[ch * CHUNK + i];
                p[i] = v.x * w4.x + v.y * w4.y + v.z * w4.z + v.w * w4.w;
            }
            // Wave-64 butterfly (4 independent chains -> good ILP).
            #pragma unroll
            for (int off = 32; off; off >>= 1) {
                #pragma unroll
                for (int i = 0; i < CHUNK; ++i)
                    p[i] += __shfl_down(p[i], off, 64);
            }
            // Cross-wave via 128 B LDS, double-buffered -> 1 barrier/chunk.
            const int slot = ch & 1;
            if (lane == 0) {
                #pragma unroll
                for (int i = 0; i < CHUNK; ++i)
                    red[slot][i][wv] = p[i];
            }
            __syncthreads();

            #pragma unroll
            for (int i = 0; i < CHUNK; ++i) {
                const float4 rr = *(const float4*)red[slot][i];  // broadcast
                const float s = (rr.x + rr.y) + (rr.z + rr.w);
                float4 v = res[ch * CHUNK + i];
                float4 xi = v;                 // layer 0: x0 == res
                if (!first) xi = xv[i];
                float4 n;
                n.x = fmaf(xi.x, s, v.x) + b4.x;
                n.y = fmaf(xi.y, s, v.y) + b4.y;
                n.z = fmaf(xi.z, s, v.z) + b4.z;
                n.w = fmaf(xi.w, s, v.w) + b4.w;
                res[ch * CHUNK + i] = n;
                asum.x += n.x; asum.y += n.y; asum.z += n.z; asum.w += n.w;
                asq.x = fmaf(n.x, n.x, asq.x);
                asq.y = fmaf(n.y, n.y, asq.y);
                asq.z = fmaf(n.z, n.z, asq.z);
                asq.w = fmaf(n.w, n.w, asq.w);
            }

            // Rotate prefetch buffer (compile-time indices only).
            if (!first && ch + 1 < NCHUNK) {
                #pragma unroll
                for (int i = 0; i < CHUNK; ++i) xv[i] = xn[i];
            }
        }

        // Per-block column partials (thread exclusively owns its 4 cols).
        *(float4*)(Psum + (size_t)blk * DD + c) = asum;
        *(float4*)(Psq  + (size_t)blk * DD + c) = asq;

        grid_barrier(sync_, 2 * l);

        // Column stats: blocks 0..255, wave 0, 4 columns per block.
        // lane k sums partial rows {k, k+64, ..., k+448}; then butterfly.
        if (blk < STATB && wv == 0) {
            const int cj = blk * 4;
            float4 s4 = make_float4(0.f, 0.f, 0.f, 0.f);
            float4 q4 = make_float4(0.f, 0.f, 0.f, 0.f);
            #pragma unroll
            for (int i = 0; i < GRID_ / 64; ++i) {
                const size_t off = (size_t)(lane + i * 64) * DD + cj;
                const float4 ps = *(const float4*)(Psum + off);
                const float4 pq = *(const float4*)(Psq + off);
                s4.x += ps.x; s4.y += ps.y; s4.z += ps.z; s4.w += ps.w;
                q4.x += pq.x; q4.y += pq.y; q4.z += pq.z; q4.w += pq.w;
            }
            #pragma unroll
            for (int off = 32; off; off >>= 1) {
                s4.x += __shfl_down(s4.x, off, 64);
                s4.y += __shfl_down(s4.y, off, 64);
                s4.z += __shfl_down(s4.z, off, 64);
                s4.w += __shfl_down(s4.w, off, 64);
                q4.x += __shfl_down(q4.x, off, 64);
                q4.y += __shfl_down(q4.y, off, 64);
                q4.z += __shfl_down(q4.z, off, 64);
                q4.w += __shfl_down(q4.w, off, 64);
            }
            if (lane == 0) {
                const float invB = 1.0f / BB;
                float4 mu, inv, sh;
                mu.x = s4.x * invB; mu.y = s4.y * invB;
                mu.z = s4.z * invB; mu.w = s4.w * invB;
                inv.x = rsqrtf(q4.x * invB - mu.x * mu.x + BN_EPS);
                inv.y = rsqrtf(q4.y * invB - mu.y * mu.y + BN_EPS);
                inv.z = rsqrtf(q4.z * invB - mu.z * mu.z + BN_EPS);
                inv.w = rsqrtf(q4.w * invB - mu.w * mu.w + BN_EPS);
                sh.x = -mu.x * inv.x; sh.y = -mu.y * inv.y;
                sh.z = -mu.z * inv.z; sh.w = -mu.w * inv.w;
                *(float4*)(scale + cj) = inv;
                *(float4*)(shift + cj) = sh;
            }
        }

        grid_barrier(sync_, 2 * l + 1);

        // Apply BN to the register-resident residual.
        const float4 sc4 = *(const float4*)(scale + c);
        const float4 sh4 = *(const float4*)(shift + c);
        #pragma unroll
        for (int i = 0; i < ROWS; ++i) {
            float4 v = res[i];
            v.x = fmaf(v.x, sc4.x, sh4.x);
            v.y = fmaf(v.y, sc4.y, sh4.y);
            v.z = fmaf(v.z, sc4.z, sh4.z);
            v.w = fmaf(v.w, sc4.w, sh4.w);
            res[i] = v;
        }
    }

    // Final residual (post-BN of layer 3) -> output.
    #pragma unroll
    for (int i = 0; i < ROWS; ++i)
        *(float4*)(out + (size_t)(r0 + i) * DD + c) = res[i];
}

extern "C" void kernel_launch(void* const* d_in, const int* in_sizes, int n_in,
                              void* d_out, int out_size, void* d_ws, size_t ws_size,
                              hipStream_t stream) {
    const float* x  = (const float*)d_in[0];   // (B, D)
    const float* ww = (const float*)d_in[1];   // (NL, D)
    const float* wb = (const float*)d_in[2];   // (NL, D)
    float* out = (float*)d_out;
    float* ws  = (float*)d_ws;

    // Workspace: 2 * GRID_ * D + 2 * D + NSYNC floats (~4 MB).
    float* Psum  = ws;                          // GRID_ * D
    float* Psq   = Psum + (size_t)GRID_ * DD;   // GRID_ * D
    float* scale = Psq  + (size_t)GRID_ * DD;   // D
    float* shift = scale + DD;                  // D
    unsigned int* sync_ = (unsigned int*)(shift + DD);  // NSYNC counters

    // Workspace is poisoned each iteration: re-zero barrier counters inside
    // the captured graph, before the persistent kernel.
    init_sync<<<1, 64, 0, stream>>>(sync_);
    crossnet_persistent<<<GRID_, NTHR, 0, stream>>>(
        x, ww, wb, out, Psum, Psq, scale, shift, sync_);
}